// Round 2
// baseline (573.727 us; speedup 1.0000x reference)
//
#include <hip/hip_runtime.h>
#include <stdint.h>

#define H_DIM 128   // hidden width (fixed by weight shapes)
#define D_IN  64    // input feature dim (fixed by weight shapes)

typedef __attribute__((ext_vector_type(8))) short bf16x8;
typedef __attribute__((ext_vector_type(4))) float f32x4;

// ---------------- threefry2x32-20, bit-exact with JAX ----------------
__host__ __device__ __forceinline__ void tf2x32(uint32_t k0, uint32_t k1,
    uint32_t x0, uint32_t x1, uint32_t* o0, uint32_t* o1)
{
  uint32_t ks0 = k0, ks1 = k1, ks2 = k0 ^ k1 ^ 0x1BD11BDAu;
  x0 += ks0; x1 += ks1;
#define TFR(r) { x0 += x1; x1 = (x1 << (r)) | (x1 >> (32-(r))); x1 ^= x0; }
  TFR(13) TFR(15) TFR(26) TFR(6)   x0 += ks1; x1 += ks2 + 1u;
  TFR(17) TFR(29) TFR(16) TFR(24)  x0 += ks2; x1 += ks0 + 2u;
  TFR(13) TFR(15) TFR(26) TFR(6)   x0 += ks0; x1 += ks1 + 3u;
  TFR(17) TFR(29) TFR(16) TFR(24)  x0 += ks1; x1 += ks2 + 4u;
  TFR(13) TFR(15) TFR(26) TFR(6)   x0 += ks2; x1 += ks0 + 5u;
#undef TFR
  *o0 = x0; *o1 = x1;
}

__device__ __forceinline__ float bfu(unsigned short u){
  return __uint_as_float(((unsigned int)u) << 16);
}
__device__ __forceinline__ unsigned short f2bf(float f){  // RNE
  unsigned int u = __float_as_uint(f);
  u += 0x7fffu + ((u >> 16) & 1u);
  return (unsigned short)(u >> 16);
}

// bf16 transposed weight layout (ushort offsets): WtIn[128][64], WtC0[128][128], WtC1[128][128]
#define WT_IN  0
#define WT_C0  8192
#define WT_C1  24576
#define WT_TOT 40960

// ---- prep: zero cnt  +  build bf16 transposed weights straight from f32 inputs ----
__global__ __launch_bounds__(256) void k_prep(int* __restrict__ cnt, int zb, int N,
    const float* __restrict__ W_in, const float* __restrict__ Wc,
    unsigned short* __restrict__ wt)
{
  int b = blockIdx.x;
  if (b < zb){
    int i = b*256 + threadIdx.x;
    if (i < N) cnt[i] = 0;
  } else {
    int idx = (b - zb)*256 + threadIdx.x;
    if (idx >= WT_TOT) return;
    if (idx < WT_C0){                 // WtIn[n][k] = W_in[k][n], n<128, k<64
      int n = idx >> 6, k = idx & 63;
      wt[idx] = f2bf(W_in[k*128 + n]);
    } else if (idx < WT_C1){          // WtC0[n][k] = Wc0[k][n]
      int r = idx - WT_C0; int n = r >> 7, k = r & 127;
      wt[idx] = f2bf(Wc[k*128 + n]);
    } else {                          // WtC1[n][k] = Wc1[k][n]
      int r = idx - WT_C1; int n = r >> 7, k = r & 127;
      wt[idx] = f2bf(Wc[16384 + k*128 + n]);
    }
  }
}

// ---------------- CSR build (scan kernels) ----------------
__global__ __launch_bounds__(256) void k_scan1(const int* __restrict__ cnt, int* __restrict__ bsum, int N){
  int tid = threadIdx.x;
  int base = blockIdx.x*1024 + tid*4;
  int s = 0;
  #pragma unroll
  for (int j=0;j<4;++j){ int idx = base+j; if (idx < N) s += cnt[idx]; }
  __shared__ int sh[256];
  sh[tid] = s; __syncthreads();
  for (int o=128;o;o>>=1){ if (tid<o) sh[tid]+=sh[tid+o]; __syncthreads(); }
  if (tid==0) bsum[blockIdx.x] = sh[0];
}
__global__ __launch_bounds__(64) void k_scan2(const int* __restrict__ bsum, int* __restrict__ boff,
                                              int nb, int* __restrict__ rowptr, int N){
  if (threadIdx.x==0 && blockIdx.x==0){
    int run = 0;
    for (int b=0;b<nb;++b){ boff[b]=run; run += bsum[b]; }
    rowptr[N] = run;   // == E
  }
}
__global__ __launch_bounds__(256) void k_scan3(const int* __restrict__ cnt, const int* __restrict__ boff,
                                               int* __restrict__ rowptr, float* __restrict__ dinv, int N){
  int tid = threadIdx.x;
  int base = blockIdx.x*1024 + tid*4;
  int a[4]; int tsum = 0;
  #pragma unroll
  for (int j=0;j<4;++j){ int idx=base+j; a[j] = (idx < N) ? cnt[idx] : 0; tsum += a[j]; }
  __shared__ int sh[256];
  sh[tid] = tsum; __syncthreads();
  for (int off=1; off<256; off<<=1){
    int v = 0; if (tid>=off) v = sh[tid-off];
    __syncthreads(); sh[tid] += v; __syncthreads();
  }
  int run = boff[blockIdx.x] + (sh[tid] - tsum);
  #pragma unroll
  for (int j=0;j<4;++j){
    int idx=base+j;
    if (idx < N){
      rowptr[idx] = run;
      dinv[idx] = 1.0f / sqrtf(1.0f + (float)a[j]);
    }
    run += a[j];
  }
}

// ------- MFMA GEMM body: C[M,128] = A[M,K] @ B[K,128], f32 accum; Bt transposed bf16.
// EXT=true: A is f32 (the network input x); else bf16 activations. -------
template<int K, bool EXT, bool RELUBIAS>
__device__ __forceinline__ void gemm_body(int bx, int tid, const void* __restrict__ Av,
    const unsigned short* __restrict__ Bt, const float* __restrict__ bias,
    unsigned short* __restrict__ C, int M)
{
  const int wid  = tid >> 6;
  const int lane = tid & 63;
  const int l15  = lane & 15;
  const int quad = lane >> 4;
  const int rowBase = bx * 64;
  const int col0 = wid * 32;

  f32x4 acc[4][2];
  #pragma unroll
  for (int mt=0;mt<4;++mt)
    #pragma unroll
    for (int nt=0;nt<2;++nt) acc[mt][nt] = (f32x4){0.f,0.f,0.f,0.f};

  #pragma unroll
  for (int k0 = 0; k0 < K; k0 += 32){
    bf16x8 bf[2];
    #pragma unroll
    for (int nt=0;nt<2;++nt)
      bf[nt] = *(const bf16x8*)(Bt + (size_t)(col0 + nt*16 + l15)*K + k0 + quad*8);
    #pragma unroll
    for (int mt=0;mt<4;++mt){
      int r = rowBase + mt*16 + l15;
      if (r >= M) r = M-1;             // clamped load; store is guarded
      bf16x8 af;
      if (!EXT){
        af = *(const bf16x8*)((const unsigned short*)Av + (size_t)r*K + k0 + quad*8);
      } else {
        const float* ap = (const float*)Av + (size_t)r*K + k0 + quad*8;
        #pragma unroll
        for (int j=0;j<8;++j) ((unsigned short*)&af)[j] = f2bf(ap[j]);
      }
      #pragma unroll
      for (int nt=0;nt<2;++nt)
        acc[mt][nt] = __builtin_amdgcn_mfma_f32_16x16x32_bf16(af, bf[nt], acc[mt][nt], 0,0,0);
    }
  }

  #pragma unroll
  for (int mt=0;mt<4;++mt){
    #pragma unroll
    for (int nt=0;nt<2;++nt){
      int col = col0 + nt*16 + l15;
      float bb = 0.f;
      if (RELUBIAS) bb = bias[col];
      #pragma unroll
      for (int reg=0;reg<4;++reg){
        int row = rowBase + mt*16 + quad*4 + reg;
        if (row < M){
          float vv = acc[mt][nt][reg];
          if (RELUBIAS) vv = fmaxf(vv + bb, 0.f);
          C[(size_t)row*128 + col] = f2bf(vv);
        }
      }
    }
  }
}

template<int K, bool EXT, bool RELUBIAS>
__global__ __launch_bounds__(256) void gemm_mfma(const void* __restrict__ Av,
    const unsigned short* __restrict__ Bt, const float* __restrict__ bias,
    unsigned short* __restrict__ C, int M)
{
  gemm_body<K,EXT,RELUBIAS>(blockIdx.x, threadIdx.x, Av, Bt, bias, C, M);
}

// ---- fusion 1: input GEMM + edge-count (independent; overlap on the grid) ----
__global__ __launch_bounds__(256) void fused_gemmIn_count(const float* __restrict__ x,
    const unsigned short* __restrict__ Bt, const float* __restrict__ bias,
    unsigned short* __restrict__ C, int N, int gB,
    const int* __restrict__ dst, int* __restrict__ cnt, int* __restrict__ perm, int E)
{
  int bx = blockIdx.x;
  if (bx < gB){
    gemm_body<64,true,true>(bx, threadIdx.x, x, Bt, bias, C, N);
  } else {
    int e = (bx - gB)*256 + threadIdx.x;
    if (e < E){
      int p = atomicAdd(&cnt[dst[e]], 1);
      perm[e] = p;
    }
  }
}

// ---- fusion 2: layer-0 GEMM + CSR fill (independent; overlap on the grid) ----
// CSR entry = (src byte-offset, fused coefficient dinv[src]*dinv[dst])
__global__ __launch_bounds__(256) void fused_gemmL0_fill(const unsigned short* __restrict__ A,
    const unsigned short* __restrict__ Bt, unsigned short* __restrict__ C, int N, int gB,
    const int* __restrict__ src, const int* __restrict__ dst,
    const int* __restrict__ rowptr, const int* __restrict__ perm,
    const float* __restrict__ dinv, int2* __restrict__ csr2, int E)
{
  int bx = blockIdx.x;
  if (bx < gB){
    gemm_body<128,false,false>(bx, threadIdx.x, A, Bt, nullptr, C, N);
  } else {
    int e = (bx - gB)*256 + threadIdx.x;
    if (e < E){
      int d = dst[e];
      int s = src[e];
      float cf = dinv[s]*dinv[d];
      csr2[rowptr[d] + perm[e]] = make_int2(s << 8, __float_as_int(cf));  // s*256 bytes
    }
  }
}

// ---- gather: half-wave scheme. Each lane owns 4 cols (8B dwordx2); the two
// 32-lane halves process alternating edges; cross-half combine via shfl_xor(32). ----
__global__ __launch_bounds__(256) void gcn_gather(const unsigned short* __restrict__ t,
    const int* __restrict__ rowptr, const int2* __restrict__ csr2,
    const float* __restrict__ dinv, const float* __restrict__ bcw,
    unsigned short* __restrict__ v, double* __restrict__ part, int N)
{
  int node = (int)((blockIdx.x*256u + threadIdx.x) >> 6);
  int lane = threadIdx.x & 63;
  int half = lane >> 5;
  int l32  = lane & 31;
  const char* tl = (const char*)t + l32*8;   // lane owns cols 4*l32 .. 4*l32+3
  float a0=0.f, a1=0.f, a2=0.f, a3=0.f;
  float ls = 0.f, lss = 0.f;
  if (node < N){
    int e0 = rowptr[node], e1 = rowptr[node+1];
    int e = e0 + half;
    for (; e + 6 < e1; e += 8){        // 4 edges per half per iter (8 per wave)
      int2 p[4];
      #pragma unroll
      for (int q=0;q<4;++q) p[q] = csr2[e + 2*q];
      uint2 rv[4];
      #pragma unroll
      for (int q=0;q<4;++q) rv[q] = *(const uint2*)(tl + (unsigned int)p[q].x);
      #pragma unroll
      for (int q=0;q<4;++q){
        float c = __int_as_float(p[q].y);
        a0 = fmaf(__uint_as_float(rv[q].x << 16),          c, a0);
        a1 = fmaf(__uint_as_float(rv[q].x & 0xffff0000u),  c, a1);
        a2 = fmaf(__uint_as_float(rv[q].y << 16),          c, a2);
        a3 = fmaf(__uint_as_float(rv[q].y & 0xffff0000u),  c, a3);
      }
    }
    for (; e < e1; e += 2){
      int2 p = csr2[e];
      float c = __int_as_float(p.y);
      uint2 rv = *(const uint2*)(tl + (unsigned int)p.x);
      a0 = fmaf(__uint_as_float(rv.x << 16),          c, a0);
      a1 = fmaf(__uint_as_float(rv.x & 0xffff0000u),  c, a1);
      a2 = fmaf(__uint_as_float(rv.y << 16),          c, a2);
      a3 = fmaf(__uint_as_float(rv.y & 0xffff0000u),  c, a3);
    }
  }
  // cross-half combine (lanes with node>=N hold zeros; harmless)
  a0 += __shfl_xor(a0, 32);
  a1 += __shfl_xor(a1, 32);
  a2 += __shfl_xor(a2, 32);
  a3 += __shfl_xor(a3, 32);
  if (node < N && half == 0){
    float dn = dinv[node];
    float dn2 = dn*dn;
    uint2 tv = *(const uint2*)(tl + ((size_t)node << 8));
    a0 = fmaf(__uint_as_float(tv.x << 16),          dn2, a0);
    a1 = fmaf(__uint_as_float(tv.x & 0xffff0000u),  dn2, a1);
    a2 = fmaf(__uint_as_float(tv.y << 16),          dn2, a2);
    a3 = fmaf(__uint_as_float(tv.y & 0xffff0000u),  dn2, a3);
    float4 bq = ((const float4*)bcw)[l32];
    a0 += bq.x; a1 += bq.y; a2 += bq.z; a3 += bq.w;
    uint2 pk;
    pk.x = (unsigned int)f2bf(a0) | ((unsigned int)f2bf(a1) << 16);
    pk.y = (unsigned int)f2bf(a2) | ((unsigned int)f2bf(a3) << 16);
    *(uint2*)((char*)v + ((size_t)node << 8) + l32*8) = pk;
    ls  = a0 + a1 + a2 + a3;
    lss = a0*a0 + a1*a1 + a2*a2 + a3*a3;
  }
  for (int off=32; off; off>>=1){ ls += __shfl_down(ls, off); lss += __shfl_down(lss, off); }
  __shared__ float ssum[4], ssq[4];
  int wv = threadIdx.x >> 6;
  int lz = threadIdx.x & 63;
  if (lz==0){ ssum[wv]=ls; ssq[wv]=lss; }
  __syncthreads();
  if (threadIdx.x==0){
    part[2*blockIdx.x]   = (double)(ssum[0]+ssum[1]+ssum[2]+ssum[3]);
    part[2*blockIdx.x+1] = (double)(ssq[0]+ssq[1]+ssq[2]+ssq[3]);
  }
}

// ---- reduce per-block partials -> red[0..1] (single block) ----
__global__ __launch_bounds__(256) void k_reduce(const double* __restrict__ part,
                                                int nblocks, double* __restrict__ red){
  int tid = threadIdx.x;
  double s = 0.0, q = 0.0;
  for (int i = tid; i < nblocks; i += 256){
    s += part[2*i];
    q += part[2*i+1];
  }
  __shared__ double shs[256], shq[256];
  shs[tid] = s; shq[tid] = q; __syncthreads();
  for (int o=128;o;o>>=1){
    if (tid<o){ shs[tid]+=shs[tid+o]; shq[tid]+=shq[tid+o]; }
    __syncthreads();
  }
  if (tid==0){ red[0]=shs[0]; red[1]=shq[0]; }
}

// -------- LayerNorm(graph) + ReLU + dropout, 2 elems/thread (threefry XOR-fold — VERIFIED R10) --------
__global__ __launch_bounds__(256) void ln_relu_drop(const unsigned short* __restrict__ v,
    unsigned short* __restrict__ h, const double* __restrict__ red,
    const float* __restrict__ gammaf, const float* __restrict__ betaf,
    uint32_t k0, uint32_t k1, int total, double tot)
{
  int i = blockIdx.x*256 + threadIdx.x;     // uint (2-element) index
  int j0 = i*2;
  if (j0 >= total) return;
  double S = red[0], Q = red[1];
  double mu_d = S / tot;
  double var_d = Q / tot - mu_d*mu_d;
  if (var_d < 0.0) var_d = 0.0;
  float mu  = (float)mu_d;
  float inv = 1.0f / ((float)sqrt(var_d) + 1e-5f);

  unsigned int hv = ((const unsigned int*)v)[i];
  float x0 = __uint_as_float(hv << 16);
  float x1 = __uint_as_float(hv & 0xffff0000u);

  uint32_t b0, b1;
  tf2x32(k0, k1, 0u, (uint32_t)j0, &b0, &b1);
  float u0 = __uint_as_float(((b0 ^ b1) >> 9) | 0x3f800000u) - 1.0f;
  tf2x32(k0, k1, 0u, (uint32_t)(j0+1), &b0, &b1);
  float u1 = __uint_as_float(((b0 ^ b1) >> 9) | 0x3f800000u) - 1.0f;

  int c0 = j0 & (H_DIM-1);                  // even
  float2 g  = ((const float2*)gammaf)[c0 >> 1];
  float2 be = ((const float2*)betaf)[c0 >> 1];
  float y0 = fmaf((x0 - mu)*inv, g.x, be.x);
  float y1 = fmaf((x1 - mu)*inv, g.y, be.y);
  y0 = fmaxf(y0, 0.f);
  y1 = fmaxf(y1, 0.f);
  y0 = (u0 < 0.8f) ? (y0 / 0.8f) : 0.f;
  y1 = (u1 < 0.8f) ? (y1 / 0.8f) : 0.f;
  unsigned int pk = (unsigned int)f2bf(y0) | ((unsigned int)f2bf(y1) << 16);
  ((unsigned int*)h)[i] = pk;
}

// -------- fused: LN + ReLU + dropout + out-GEMM + softmax (final layer; skips h round-trip) --------
__global__ __launch_bounds__(256) void ln_out_softmax(const unsigned short* __restrict__ v,
    const double* __restrict__ red, const float* __restrict__ gammaf, const float* __restrict__ betaf,
    uint32_t k0, uint32_t k1, const float* __restrict__ Wo, const float* __restrict__ bo,
    float2* __restrict__ outv, int N, double tot)
{
  int node = (int)((blockIdx.x*256u + threadIdx.x) >> 6);
  int lane = threadIdx.x & 63;
  if (node >= N) return;
  double S = red[0], Q = red[1];
  double mu_d = S / tot;
  double var_d = Q / tot - mu_d*mu_d;
  if (var_d < 0.0) var_d = 0.0;
  float mu  = (float)mu_d;
  float inv = 1.0f / ((float)sqrt(var_d) + 1e-5f);

  unsigned int hv = ((const unsigned int*)(v + (size_t)node*H_DIM))[lane];
  float x0 = __uint_as_float(hv << 16);
  float x1 = __uint_as_float(hv & 0xffff0000u);

  int j0 = node*H_DIM + 2*lane;
  uint32_t b0, b1;
  tf2x32(k0, k1, 0u, (uint32_t)j0, &b0, &b1);
  float u0 = __uint_as_float(((b0 ^ b1) >> 9) | 0x3f800000u) - 1.0f;
  tf2x32(k0, k1, 0u, (uint32_t)(j0+1), &b0, &b1);
  float u1 = __uint_as_float(((b0 ^ b1) >> 9) | 0x3f800000u) - 1.0f;

  float2 g  = ((const float2*)gammaf)[lane];
  float2 be = ((const float2*)betaf)[lane];
  float y0 = fmaf((x0 - mu)*inv, g.x, be.x);
  float y1 = fmaf((x1 - mu)*inv, g.y, be.y);
  y0 = fmaxf(y0, 0.f);
  y1 = fmaxf(y1, 0.f);
  y0 = (u0 < 0.8f) ? (y0 / 0.8f) : 0.f;
  y1 = (u1 < 0.8f) ? (y1 / 0.8f) : 0.f;

  float4 wq = ((const float4*)Wo)[lane];   // Wo[2l][0],Wo[2l][1],Wo[2l+1][0],Wo[2l+1][1]
  float d0 = y0*wq.x + y1*wq.z;
  float d1 = y0*wq.y + y1*wq.w;
  for (int off=32; off; off>>=1){ d0 += __shfl_down(d0, off); d1 += __shfl_down(d1, off); }
  if (lane==0){
    d0 += bo[0]; d1 += bo[1];
    float m = fmaxf(d0, d1);
    float e0 = expf(d0 - m), e1 = expf(d1 - m);
    float s = e0 + e1;
    outv[node] = make_float2(e0/s, e1/s);
  }
}

// ---------------- launch ----------------
extern "C" void kernel_launch(void* const* d_in, const int* in_sizes, int n_in,
                              void* d_out, int out_size, void* d_ws, size_t ws_size,
                              hipStream_t stream) {
  (void)n_in; (void)out_size; (void)ws_size;
  const int N = in_sizes[0] / D_IN;     // x is [N, 64]
  const int E = in_sizes[1] / 2;        // edge_index is [2, E]
  const int total = N * H_DIM;
  const double tot = (double)total;

  const float* x    = (const float*)d_in[0];
  const int*   ei   = (const int*)d_in[1];
  const float* W_in = (const float*)d_in[2];
  const float* b_in = (const float*)d_in[3];
  const float* Wc   = (const float*)d_in[4];
  const float* bc   = (const float*)d_in[5];
  const float* gam  = (const float*)d_in[6];
  const float* bet  = (const float*)d_in[7];
  const float* W_o  = (const float*)d_in[8];
  const float* b_o  = (const float*)d_in[9];
  const int* src = ei;
  const int* dst = ei + E;
  char* ws = (char*)d_ws;

  const int nb = (N + 1023) >> 10;      // scan blocks
  const int nodeBlocks = (N + 3) / 4;   // 64 lanes per node
  const int zb = (N + 255) / 256;
  const int edgeBlocks = (E + 255) / 256;

  // runtime workspace layout, 256B-aligned slabs (~72 MB)
  size_t o = 0;
  auto take = [&](size_t bytes)->char*{ char* p = ws + o; o = (o + bytes + 255) & ~(size_t)255; return p; };
  double* red    = (double*)take(4*sizeof(double));
  double* part   = (double*)take((size_t)nodeBlocks*2*sizeof(double));
  float*  dinv   = (float*) take((size_t)N*4);
  int*    cnt    = (int*)   take((size_t)N*4);
  int*    rowptr = (int*)   take(((size_t)N+1)*4);
  int*    bsum   = (int*)   take((size_t)nb*4);
  int*    boff   = (int*)   take((size_t)nb*4);
  unsigned short* wt = (unsigned short*)take((size_t)WT_TOT*2);
  int2*   csr2   = (int2*)  take((size_t)E*8);
  int*    perm   = (int*)   take((size_t)E*4);
  unsigned short* actA = (unsigned short*)take((size_t)total*2);
  unsigned short* actB = (unsigned short*)take((size_t)total*2);

  // fold_in(key(1), i) = tf2x32(key=(0,1), counter=[0,i]) — verified
  uint32_t k00,k01,k10,k11;
  tf2x32(0u,1u,0u,0u,&k00,&k01);
  tf2x32(0u,1u,0u,1u,&k10,&k11);

  const int gemmBlocks = (N + 63) / 64;
  const int lnBlocks = (total/2 + 255) / 256;

  k_prep  <<<zb + (WT_TOT+255)/256, 256,0,stream>>>(cnt, zb, N, W_in, Wc, wt);

  // input GEMM (relu(x@W_in+b_in)) overlapped with edge counting
  fused_gemmIn_count<<<gemmBlocks + edgeBlocks, 256,0,stream>>>(
      x, wt+WT_IN, b_in, actA, N, gemmBlocks, dst, cnt, perm, E);

  k_scan1 <<<nb,  256,0,stream>>>(cnt, bsum, N);
  k_scan2 <<<1,    64,0,stream>>>(bsum, boff, nb, rowptr, N);
  k_scan3 <<<nb,  256,0,stream>>>(cnt, boff, rowptr, dinv, N);

  // layer-0 GEMM overlapped with CSR fill
  fused_gemmL0_fill<<<gemmBlocks + edgeBlocks, 256,0,stream>>>(
      actA, wt+WT_C0, actB, N, gemmBlocks, src, dst, rowptr, perm, dinv, csr2, E);

  // layer 0: gather + stats -> LN/relu/dropout
  gcn_gather<<<nodeBlocks,256,0,stream>>>(actB, rowptr, csr2, dinv, bc, actA, part, N);
  k_reduce<<<1,256,0,stream>>>(part, nodeBlocks, red);
  ln_relu_drop<<<lnBlocks,256,0,stream>>>(actA, actB, red, gam, bet, k00, k01, total, tot);

  // layer 1: GEMM -> gather + stats -> fused LN+out+softmax (no h round-trip)
  gemm_mfma<128,false,false><<<gemmBlocks,256,0,stream>>>(actB, wt+WT_C1, nullptr, actA, N);
  gcn_gather<<<nodeBlocks,256,0,stream>>>(actA, rowptr, csr2, dinv, bc + 128, actB, part, N);
  k_reduce<<<1,256,0,stream>>>(part, nodeBlocks, red+2);
  ln_out_softmax<<<nodeBlocks,256,0,stream>>>(actB, red+2, gam + 128, bet + 128,
      k10, k11, W_o, b_o, (float2*)d_out, N, tot);
}